// Round 2
// baseline (211.559 us; speedup 1.0000x reference)
//
#include <hip/hip_runtime.h>
#include <math.h>

#define N_ROWS 16384
#define M_COLS 8192
#define TPB 256
#define IT 4                        // i-rows per thread (ILP chains)
#define JT 128                      // j-tile per block (LDS staged)
#define NJ (M_COLS / JT)            // 64 j-chunks
#define NIB (N_ROWS / (TPB * IT))   // 16 i-blocks
#define PAIR_BLOCKS (NIB * NJ)      // 1024
#define EDGE_BLOCKS 1024

// ---------- kernel 1: row softmax + sum-of-squares + exp(gamma) ----------
__global__ __launch_bounds__(TPB) void rownorm_kernel(
    const float* __restrict__ latent, const float* __restrict__ gamma,
    float* __restrict__ zout, float* __restrict__ sqout,
    float* __restrict__ egout, int n)
{
    int i = blockIdx.x * TPB + threadIdx.x;
    if (i >= n) return;
    const float4* src = (const float4*)(latent + (size_t)i * 8);
    float4 a = src[0], b = src[1];
    float v[8] = {a.x, a.y, a.z, a.w, b.x, b.y, b.z, b.w};
    float m = v[0];
    #pragma unroll
    for (int d = 1; d < 8; d++) m = fmaxf(m, v[d]);
    float s = 0.f;
    #pragma unroll
    for (int d = 0; d < 8; d++) { v[d] = __expf(v[d] - m); s += v[d]; }
    float inv = 1.f / s;
    float sq = 0.f;
    #pragma unroll
    for (int d = 0; d < 8; d++) { v[d] *= inv; sq = fmaf(v[d], v[d], sq); }
    float4 o0 = {v[0], v[1], v[2], v[3]};
    float4 o1 = {v[4], v[5], v[6], v[7]};
    float4* dst = (float4*)(zout + (size_t)i * 8);
    dst[0] = o0; dst[1] = o1;
    sqout[i] = sq;
    egout[i] = __expf(gamma[i]);
}

// ---------- kernel 2: pairwise sum  S = sum_ij eg_i * exp(-dist_ij) * ec_j ----------
__global__ __launch_bounds__(TPB) void pair_kernel(
    const float* __restrict__ z, const float* __restrict__ zz,
    const float* __restrict__ eg,
    const float* __restrict__ w, const float* __restrict__ ww,
    const float* __restrict__ ec,
    double* __restrict__ partials)
{
    __shared__ float sw[JT * 8];   // w tile, row-major [JT][8]
    __shared__ float swq[JT];      // ||w_j||^2
    __shared__ float sec[JT];      // exp(gamma_cols[j])
    __shared__ double sred[TPB];

    const int t = threadIdx.x;
    const int ib = blockIdx.x / NJ;
    const int jb = blockIdx.x - ib * NJ;
    const int j0 = jb * JT;

    // cooperative tile load: 256 threads x 1 float4 = 128 rows x 8 floats
    ((float4*)sw)[t] = ((const float4*)(w + (size_t)j0 * 8))[t];
    if (t < JT) { swq[t] = ww[j0 + t]; sec[t] = ec[j0 + t]; }

    // per-thread i-rows in registers, pre-scaled by -2 so
    // sq = (zz + wq) + sum_d (-2*z_d)*w_d  folds into a pure FMA chain
    float zi[IT][8], zzi[IT], egi[IT], acc[IT];
    #pragma unroll
    for (int k = 0; k < IT; k++) {
        int i = ib * (TPB * IT) + k * TPB + t;
        const float4* zp = (const float4*)(z + (size_t)i * 8);
        float4 a = zp[0], b = zp[1];
        zi[k][0] = -2.f * a.x; zi[k][1] = -2.f * a.y;
        zi[k][2] = -2.f * a.z; zi[k][3] = -2.f * a.w;
        zi[k][4] = -2.f * b.x; zi[k][5] = -2.f * b.y;
        zi[k][6] = -2.f * b.z; zi[k][7] = -2.f * b.w;
        zzi[k] = zz[i]; egi[k] = eg[i]; acc[k] = 0.f;
    }
    __syncthreads();

    for (int j = 0; j < JT; j++) {
        // wave-uniform address -> LDS broadcast (conflict-free)
        float4 wa = ((const float4*)sw)[j * 2];
        float4 wb = ((const float4*)sw)[j * 2 + 1];
        float wq = swq[j];
        float e  = sec[j];
        #pragma unroll
        for (int k = 0; k < IT; k++) {
            float sq = zzi[k] + wq;
            sq = fmaf(zi[k][0], wa.x, sq);
            sq = fmaf(zi[k][1], wa.y, sq);
            sq = fmaf(zi[k][2], wa.z, sq);
            sq = fmaf(zi[k][3], wa.w, sq);
            sq = fmaf(zi[k][4], wb.x, sq);
            sq = fmaf(zi[k][5], wb.y, sq);
            sq = fmaf(zi[k][6], wb.z, sq);
            sq = fmaf(zi[k][7], wb.w, sq);
            float d  = sqrtf(fmaxf(sq, 0.f));
            acc[k] = fmaf(e, __expf(-d), acc[k]);
        }
    }

    double tp = 0.0;
    #pragma unroll
    for (int k = 0; k < IT; k++) tp += (double)egi[k] * (double)acc[k];

    sred[t] = tp;
    __syncthreads();
    for (int s = TPB / 2; s > 0; s >>= 1) {
        if (t < s) sred[t] += sred[t + s];
        __syncthreads();
    }
    if (t == 0) partials[blockIdx.x] = sred[0];
}

// ---------- kernel 3: edge term  sum_e w_e*(gr[r]+gc[c]-dist_e) ----------
__global__ __launch_bounds__(TPB) void edge_kernel(
    const float* __restrict__ z, const float* __restrict__ w,
    const float* __restrict__ gr, const float* __restrict__ gc,
    const float* __restrict__ wt,
    const int* __restrict__ ridx, const int* __restrict__ cidx,
    int E, double* __restrict__ partials)
{
    __shared__ double sred[TPB];
    const int t = threadIdx.x;
    int tid = blockIdx.x * TPB + t;
    int stride = gridDim.x * TPB;
    double local = 0.0;
    for (int e = tid; e < E; e += stride) {
        int r = ridx[e], c = cidx[e];
        const float4* zp = (const float4*)(z + (size_t)r * 8);
        const float4* wp = (const float4*)(w + (size_t)c * 8);
        float4 za = zp[0], zb = zp[1], wa = wp[0], wb = wp[1];
        float d0 = za.x - wa.x, d1 = za.y - wa.y, d2 = za.z - wa.z, d3 = za.w - wa.w;
        float d4 = zb.x - wb.x, d5 = zb.y - wb.y, d6 = zb.z - wb.z, d7 = zb.w - wb.w;
        float s = d0 * d0;
        s = fmaf(d1, d1, s); s = fmaf(d2, d2, s); s = fmaf(d3, d3, s);
        s = fmaf(d4, d4, s); s = fmaf(d5, d5, s); s = fmaf(d6, d6, s);
        s = fmaf(d7, d7, s);
        float dist = sqrtf(s);
        local += (double)(wt[e] * (gr[r] + gc[c] - dist));
    }
    sred[t] = local;
    __syncthreads();
    for (int s2 = TPB / 2; s2 > 0; s2 >>= 1) {
        if (t < s2) sred[t] += sred[t + s2];
        __syncthreads();
    }
    if (t == 0) partials[blockIdx.x] = sred[0];
}

// ---------- kernel 4: final deterministic combine ----------
__global__ __launch_bounds__(TPB) void final_kernel(
    const double* __restrict__ pp, int np,
    const double* __restrict__ ep, int ne,
    float* __restrict__ out)
{
    __shared__ double sred[TPB];
    const int t = threadIdx.x;
    double s1 = 0.0, s2 = 0.0;
    for (int i = t; i < np; i += TPB) s1 += pp[i];
    for (int i = t; i < ne; i += TPB) s2 += ep[i];
    sred[t] = s1;
    __syncthreads();
    for (int s = TPB / 2; s > 0; s >>= 1) {
        if (t < s) sred[t] += sred[t + s];
        __syncthreads();
    }
    double pair_sum = sred[0];
    __syncthreads();
    sred[t] = s2;
    __syncthreads();
    for (int s = TPB / 2; s > 0; s >>= 1) {
        if (t < s) sred[t] += sred[t + s];
        __syncthreads();
    }
    if (t == 0) {
        double edge_sum = sred[0];
        // z_pdist1 = exp(-EPS) * pair_sum ; result = z_pdist1 - z_pdist2
        double cf = exp(-1.0e-6);
        out[0] = (float)(cf * pair_sum - edge_sum);
    }
}

extern "C" void kernel_launch(void* const* d_in, const int* in_sizes, int n_in,
                              void* d_out, int out_size, void* d_ws, size_t ws_size,
                              hipStream_t stream)
{
    const float* gamma_rows = (const float*)d_in[0];   // [N]
    const float* gamma_cols = (const float*)d_in[1];   // [M]
    const float* latent_z   = (const float*)d_in[2];   // [N,8]
    const float* latent_w   = (const float*)d_in[3];   // [M,8]
    const float* weights    = (const float*)d_in[4];   // [E]
    const int*   rows_idx   = (const int*)d_in[5];     // [E]
    const int*   col_idx    = (const int*)d_in[6];     // [E]
    float* out = (float*)d_out;
    const int E = in_sizes[4];

    // workspace layout (all segments 256B-aligned); total ~1 MB
    char* base = (char*)d_ws;
    size_t off = 0;
    float* z  = (float*)(base + off); off += (size_t)N_ROWS * 8 * 4;   // 524288
    float* zz = (float*)(base + off); off += (size_t)N_ROWS * 4;       // 65536
    float* eg = (float*)(base + off); off += (size_t)N_ROWS * 4;       // 65536
    float* w  = (float*)(base + off); off += (size_t)M_COLS * 8 * 4;   // 262144
    float* ww = (float*)(base + off); off += (size_t)M_COLS * 4;       // 32768
    float* ec = (float*)(base + off); off += (size_t)M_COLS * 4;       // 32768
    double* pair_part = (double*)(base + off); off += (size_t)PAIR_BLOCKS * 8;
    double* edge_part = (double*)(base + off); off += (size_t)EDGE_BLOCKS * 8;
    (void)ws_size;

    rownorm_kernel<<<(N_ROWS + TPB - 1) / TPB, TPB, 0, stream>>>(
        latent_z, gamma_rows, z, zz, eg, N_ROWS);
    rownorm_kernel<<<(M_COLS + TPB - 1) / TPB, TPB, 0, stream>>>(
        latent_w, gamma_cols, w, ww, ec, M_COLS);
    pair_kernel<<<PAIR_BLOCKS, TPB, 0, stream>>>(z, zz, eg, w, ww, ec, pair_part);
    edge_kernel<<<EDGE_BLOCKS, TPB, 0, stream>>>(
        z, w, gamma_rows, gamma_cols, weights, rows_idx, col_idx, E, edge_part);
    final_kernel<<<1, TPB, 0, stream>>>(pair_part, PAIR_BLOCKS,
                                        edge_part, EDGE_BLOCKS, out);
}

// Round 3
// 173.422 us; speedup vs baseline: 1.2199x; 1.2199x over previous
//
#include <hip/hip_runtime.h>
#include <math.h>

#define N_ROWS 16384
#define M_COLS 8192
#define TPB 256
#define IT 4                        // i-rows per thread (ILP chains)
#define JT 128                      // j-tile per block (LDS staged)
#define NJ (M_COLS / JT)            // 64 j-chunks
#define NIB (N_ROWS / (TPB * IT))   // 16 i-blocks
#define PAIR_BLOCKS (NIB * NJ)      // 1024
#define EDGE_BLOCKS 1024
#define FUSED_BLOCKS (PAIR_BLOCKS + EDGE_BLOCKS)   // 2048 = 8 blocks/CU

typedef float v2f __attribute__((ext_vector_type(2)));

#define LOG2E 1.4426950408889634f
#define C2 2.0813689810056077f      // log2(e)^2 — folded into the quadratic form

// ---------- kernel 1: fused row softmax for BOTH z and w ----------
// stores: simplex row (raw), C2*||row||^2, exp(gamma)
__global__ __launch_bounds__(TPB) void rownorm_kernel(
    const float* __restrict__ lz, const float* __restrict__ gr,
    const float* __restrict__ lw, const float* __restrict__ gc,
    float* __restrict__ z, float* __restrict__ zz, float* __restrict__ eg,
    float* __restrict__ w, float* __restrict__ ww, float* __restrict__ ec)
{
    int gi = blockIdx.x * TPB + threadIdx.x;
    const float *src, *g;
    float *dv, *dq, *de;
    int i;
    if (gi < N_ROWS) { src = lz; g = gr; dv = z; dq = zz; de = eg; i = gi; }
    else             { src = lw; g = gc; dv = w; dq = ww; de = ec; i = gi - N_ROWS; }

    const float4* sp = (const float4*)(src + (size_t)i * 8);
    float4 a = sp[0], b = sp[1];
    float v[8] = {a.x, a.y, a.z, a.w, b.x, b.y, b.z, b.w};
    float m = v[0];
    #pragma unroll
    for (int d = 1; d < 8; d++) m = fmaxf(m, v[d]);
    float s = 0.f;
    #pragma unroll
    for (int d = 0; d < 8; d++) { v[d] = __expf(v[d] - m); s += v[d]; }
    float inv = 1.f / s;
    float sq = 0.f;
    #pragma unroll
    for (int d = 0; d < 8; d++) { v[d] *= inv; sq = fmaf(v[d], v[d], sq); }
    float4 o0 = {v[0], v[1], v[2], v[3]};
    float4 o1 = {v[4], v[5], v[6], v[7]};
    float4* dp = (float4*)(dv + (size_t)i * 8);
    dp[0] = o0; dp[1] = o1;
    dq[i] = C2 * sq;                 // pre-scaled for the exp2 trick
    de[i] = __expf(g[i]);
}

// ---------- kernel 2: fused pair + edge (block role by parity) ----------
// even blocks: pair sum  S1 = sum_ij eg_i * exp(-dist_ij) * ec_j   (VALU-bound)
// odd  blocks: edge sum  S2 = sum_e wt_e*(gr[r]+gc[c]-dist_e)      (mem-latency-bound)
__global__ __launch_bounds__(TPB) void fused_kernel(
    const float* __restrict__ z, const float* __restrict__ zz,
    const float* __restrict__ eg,
    const float* __restrict__ w, const float* __restrict__ ww,
    const float* __restrict__ ec,
    const float* __restrict__ gr, const float* __restrict__ gc,
    const float* __restrict__ wt,
    const int* __restrict__ ridx, const int* __restrict__ cidx, int E,
    double* __restrict__ pair_part, double* __restrict__ edge_part)
{
    __shared__ float  sw[JT * 8];    // w tile [JT][8]
    __shared__ float  swq[JT];       // C2*||w_j||^2
    __shared__ float  sec[JT];       // exp(gamma_cols[j])
    __shared__ double sred[TPB];

    const int t   = threadIdx.x;
    const int rid = blockIdx.x >> 1;

    if ((blockIdx.x & 1) == 0) {
        // ================= PAIR ROLE =================
        const int ib = rid / NJ;
        const int jb = rid - ib * NJ;
        const int j0 = jb * JT;

        ((float4*)sw)[t] = ((const float4*)(w + (size_t)j0 * 8))[t];
        if (t < JT) { swq[t] = ww[j0 + t]; sec[t] = ec[j0 + t]; }

        // z rows pre-scaled by -2*C2: sq' = C2*(zz+ww-2dot) accumulates as pure pk-FMA
        v2f  zi[IT][4];
        float zzi[IT], acc[IT];
        const int ibase = ib * (TPB * IT);
        #pragma unroll
        for (int k = 0; k < IT; k++) {
            int i = ibase + k * TPB + t;
            const float4* zp = (const float4*)(z + (size_t)i * 8);
            float4 a = zp[0], b = zp[1];
            zi[k][0] = (v2f){-2.f * C2 * a.x, -2.f * C2 * a.y};
            zi[k][1] = (v2f){-2.f * C2 * a.z, -2.f * C2 * a.w};
            zi[k][2] = (v2f){-2.f * C2 * b.x, -2.f * C2 * b.y};
            zi[k][3] = (v2f){-2.f * C2 * b.z, -2.f * C2 * b.w};
            zzi[k] = zz[i];
            acc[k] = 0.f;
        }
        __syncthreads();

        for (int j = 0; j < JT; j++) {
            float4 wa = ((const float4*)sw)[j * 2];
            float4 wb = ((const float4*)sw)[j * 2 + 1];
            v2f w01 = {wa.x, wa.y}, w23 = {wa.z, wa.w};
            v2f w45 = {wb.x, wb.y}, w67 = {wb.z, wb.w};
            float wq = swq[j];
            float e  = sec[j];
            #pragma unroll
            for (int k = 0; k < IT; k++) {
                v2f p = {zzi[k], wq};
                p = __builtin_elementwise_fma(zi[k][0], w01, p);
                p = __builtin_elementwise_fma(zi[k][1], w23, p);
                p = __builtin_elementwise_fma(zi[k][2], w45, p);
                p = __builtin_elementwise_fma(zi[k][3], w67, p);
                float sq = fmaxf(p.x + p.y, 0.f);
                float d, pr;
                asm("v_sqrt_f32 %0, %1" : "=v"(d) : "v"(sq));
                asm("v_exp_f32 %0, -%1" : "=v"(pr) : "v"(d));  // 2^(-d') = e^(-dist)
                acc[k] = fmaf(e, pr, acc[k]);
            }
        }

        double tp = 0.0;
        #pragma unroll
        for (int k = 0; k < IT; k++) {
            int i = ibase + k * TPB + t;
            tp += (double)eg[i] * (double)acc[k];
        }

        sred[t] = tp;
        __syncthreads();
        for (int s = TPB / 2; s > 0; s >>= 1) {
            if (t < s) sred[t] += sred[t + s];
            __syncthreads();
        }
        if (t == 0) pair_part[rid] = sred[0];
    } else {
        // ================= EDGE ROLE =================
        int tid = rid * TPB + t;
        const int stride = EDGE_BLOCKS * TPB;
        double local = 0.0;
        #pragma unroll 2
        for (int e = tid; e < E; e += stride) {
            int r = ridx[e], c = cidx[e];
            const float4* zp = (const float4*)(z + (size_t)r * 8);
            const float4* wp = (const float4*)(w + (size_t)c * 8);
            float4 za = zp[0], zb = zp[1], wa = wp[0], wb = wp[1];
            float d0 = za.x - wa.x, d1 = za.y - wa.y, d2 = za.z - wa.z, d3 = za.w - wa.w;
            float d4 = zb.x - wb.x, d5 = zb.y - wb.y, d6 = zb.z - wb.z, d7 = zb.w - wb.w;
            float s = d0 * d0;
            s = fmaf(d1, d1, s); s = fmaf(d2, d2, s); s = fmaf(d3, d3, s);
            s = fmaf(d4, d4, s); s = fmaf(d5, d5, s); s = fmaf(d6, d6, s);
            s = fmaf(d7, d7, s);
            float dist;
            asm("v_sqrt_f32 %0, %1" : "=v"(dist) : "v"(s));
            local += (double)(wt[e] * (gr[r] + gc[c] - dist));
        }
        sred[t] = local;
        __syncthreads();
        for (int s2 = TPB / 2; s2 > 0; s2 >>= 1) {
            if (t < s2) sred[t] += sred[t + s2];
            __syncthreads();
        }
        if (t == 0) edge_part[rid] = sred[0];
    }
}

// ---------- kernel 3: final deterministic combine ----------
__global__ __launch_bounds__(TPB) void final_kernel(
    const double* __restrict__ pp, int np,
    const double* __restrict__ ep, int ne,
    float* __restrict__ out)
{
    __shared__ double sred[TPB];
    const int t = threadIdx.x;
    double s1 = 0.0, s2 = 0.0;
    for (int i = t; i < np; i += TPB) s1 += pp[i];
    for (int i = t; i < ne; i += TPB) s2 += ep[i];
    sred[t] = s1;
    __syncthreads();
    for (int s = TPB / 2; s > 0; s >>= 1) {
        if (t < s) sred[t] += sred[t + s];
        __syncthreads();
    }
    double pair_sum = sred[0];
    __syncthreads();
    sred[t] = s2;
    __syncthreads();
    for (int s = TPB / 2; s > 0; s >>= 1) {
        if (t < s) sred[t] += sred[t + s];
        __syncthreads();
    }
    if (t == 0) {
        double edge_sum = sred[0];
        double cf = exp(-1.0e-6);   // exp(-EPS) factored out of the pair term
        out[0] = (float)(cf * pair_sum - edge_sum);
    }
}

extern "C" void kernel_launch(void* const* d_in, const int* in_sizes, int n_in,
                              void* d_out, int out_size, void* d_ws, size_t ws_size,
                              hipStream_t stream)
{
    const float* gamma_rows = (const float*)d_in[0];   // [N]
    const float* gamma_cols = (const float*)d_in[1];   // [M]
    const float* latent_z   = (const float*)d_in[2];   // [N,8]
    const float* latent_w   = (const float*)d_in[3];   // [M,8]
    const float* weights    = (const float*)d_in[4];   // [E]
    const int*   rows_idx   = (const int*)d_in[5];     // [E]
    const int*   col_idx    = (const int*)d_in[6];     // [E]
    float* out = (float*)d_out;
    const int E = in_sizes[4];

    // workspace layout (segments 256B-aligned); total ~1 MB
    char* base = (char*)d_ws;
    size_t off = 0;
    float* z  = (float*)(base + off); off += (size_t)N_ROWS * 8 * 4;
    float* zz = (float*)(base + off); off += (size_t)N_ROWS * 4;
    float* eg = (float*)(base + off); off += (size_t)N_ROWS * 4;
    float* w  = (float*)(base + off); off += (size_t)M_COLS * 8 * 4;
    float* ww = (float*)(base + off); off += (size_t)M_COLS * 4;
    float* ec = (float*)(base + off); off += (size_t)M_COLS * 4;
    double* pair_part = (double*)(base + off); off += (size_t)PAIR_BLOCKS * 8;
    double* edge_part = (double*)(base + off); off += (size_t)EDGE_BLOCKS * 8;
    (void)ws_size;

    rownorm_kernel<<<(N_ROWS + M_COLS) / TPB, TPB, 0, stream>>>(
        latent_z, gamma_rows, latent_w, gamma_cols, z, zz, eg, w, ww, ec);
    fused_kernel<<<FUSED_BLOCKS, TPB, 0, stream>>>(
        z, zz, eg, w, ww, ec, gamma_rows, gamma_cols,
        weights, rows_idx, col_idx, E, pair_part, edge_part);
    final_kernel<<<1, TPB, 0, stream>>>(pair_part, PAIR_BLOCKS,
                                        edge_part, EDGE_BLOCKS, out);
}